// Round 17
// baseline (89.169 us; speedup 1.0000x reference)
//
#include <hip/hip_runtime.h>
#include <cmath>

#define BN 4096      // B*N
#define NN 64
#define GAUSS 25
#define FD 128

typedef __attribute__((ext_vector_type(8))) short bf16x8;
typedef __attribute__((ext_vector_type(4))) float f32x4;

__device__ __forceinline__ float softplus_f(float x) {
    const float t = __expf(-fabsf(x));
    return fmaxf(x, 0.f) + __logf(1.f + t);
}
// 4-op RNE emulation (R10-proven; ROCm's __float2bfloat16 adds NaN cmp/cndmask)
__device__ __forceinline__ unsigned short f2b(float f) {
    unsigned int u = __float_as_uint(f);
    unsigned int r = (u + 0x7FFFu + ((u >> 16) & 1u)) >> 16;
    return (unsigned short)r;
}
__device__ __forceinline__ bf16x8 pack8(const float4 p0, const float4 p1) {
    bf16x8 r;
    r[0] = (short)f2b(p0.x); r[1] = (short)f2b(p0.y);
    r[2] = (short)f2b(p0.z); r[3] = (short)f2b(p0.w);
    r[4] = (short)f2b(p1.x); r[5] = (short)f2b(p1.y);
    r[6] = (short)f2b(p1.z); r[7] = (short)f2b(p1.w);
    return r;
}

// ---------------------------------------------------------------------------
// KA = k0 + k1 fused (R10 config).  Grid 256 x 512.
// ---------------------------------------------------------------------------
__global__ __launch_bounds__(512) void kA_prep_embed_y(
    const float* __restrict__ emb, const int* __restrict__ zn,
    const float* __restrict__ wf1, const float* __restrict__ wf2,
    const float* __restrict__ w_in2f, const float* __restrict__ w_f2out,
    const float* __restrict__ w_dense,
    unsigned short* __restrict__ wf1tA, unsigned short* __restrict__ wf2tA,
    unsigned short* __restrict__ wf2outB, unsigned short* __restrict__ wdenseB,
    float* __restrict__ y, float* __restrict__ out)
{
    const int t = threadIdx.x;
    const int w = t >> 6, lane = t & 63, lr = lane & 15, lg = lane >> 4;
    __shared__ unsigned short s_w[16384];   // 32KB: win2fB frags

    // ---- 0a: pack global frag arrays for KB / KC ----
    {
        const int idx = blockIdx.x * 512 + t;
        if (idx < 4096) {
            const int e = idx & 7, l = (idx >> 3) & 63, ft = idx >> 9;
            const int f = ft * 16 + (l & 15);
            const int g = 8 * (l >> 4) + e;
            wf1tA[idx] = (g < GAUSS) ? f2b(wf1[g * FD + f]) : (unsigned short)0;
        } else if (idx < 20480) {
            const int i = idx - 4096;
            const int e = i & 7, l = (i >> 3) & 63, ct = (i >> 9) & 7, ks = i >> 12;
            wf2tA[i] = f2b(wf2[(ks * 32 + 8 * (l >> 4) + e) * FD + ct * 16 + (l & 15)]);
        } else if (idx < 36864) {
            const int i = idx - 20480;
            const int e = i & 7, l = (i >> 3) & 63, ct = (i >> 9) & 7, ks = i >> 12;
            wf2outB[i] = f2b(w_f2out[(ks * 32 + 8 * (l >> 4) + e) * FD + ct * 16 + (l & 15)]);
        } else if (idx < 53248) {
            const int i = idx - 36864;
            const int e = i & 7, l = (i >> 3) & 63, ct = (i >> 9) & 7, ks = i >> 12;
            wdenseB[i] = f2b(w_dense[(ks * 32 + 8 * (l >> 4) + e) * FD + ct * 16 + (l & 15)]);
        }
    }
    // ---- 0b: pack win2fB into LDS (each thread 32 consecutive slots) ----
    for (int i = t * 32, end = t * 32 + 32; i < end; ++i) {
        const int e = i & 7, l = (i >> 3) & 63, ct = (i >> 9) & 7, ks = i >> 12;
        const int col = ct * 16 + (l & 15);
        const int k = ks * 32 + 8 * (l >> 4) + e;
        s_w[i] = f2b(w_in2f[k * FD + col]);
    }
    __syncthreads();

    // ---- 1: embed + out-write + y MFMA ----
    const int atom0 = blockIdx.x * 16;
    const int atom = atom0 + lr;
    const int z = zn[atom];
    const float* xrow = emb + (size_t)z * FD;
    bf16x8 a[4];
#pragma unroll
    for (int ks = 0; ks < 4; ++ks) {
        const int c0 = ks * 32 + lg * 8;
        const float4 p0 = *(const float4*)&xrow[c0];
        const float4 p1 = *(const float4*)&xrow[c0 + 4];
        if (w == 0) {
            *(float4*)&out[(size_t)atom * 256 + c0] = p0;
            *(float4*)&out[(size_t)atom * 256 + c0 + 4] = p1;
        }
        a[ks] = pack8(p0, p1);
    }
    f32x4 acc = {0.f, 0.f, 0.f, 0.f};
#pragma unroll
    for (int ks = 0; ks < 4; ++ks)
        acc = __builtin_amdgcn_mfma_f32_16x16x32_bf16(
            a[ks], *(const bf16x8*)&s_w[((ks * 8 + w) * 64 + lane) * 8],
            acc, 0, 0, 0);
    const int col = w * 16 + lr;
#pragma unroll
    for (int r = 0; r < 4; ++r)
        y[(size_t)(atom0 + lg * 4 + r) * FD + col] = acc[r];
}

// ---------------------------------------------------------------------------
// KB: continuous-filter conv. R16 + occupancy rework:
//  - s_h1 shrunk 64->32 rows (8KB; Rt<=2 covers >99.9% of atoms) with a
//    chunked loop (2 tiles/chunk) handling rare cnt>32 correctly.
//  - __launch_bounds__(128, 6): VGPR cap ~84 -> 24 waves/CU (was 16).
// ---------------------------------------------------------------------------
__global__ __launch_bounds__(128, 6) void kB_conv(
    const float* __restrict__ pos, const float* __restrict__ cell,
    const float* __restrict__ coff, const float* __restrict__ nmask,
    const unsigned short* __restrict__ wf1tA, const float* __restrict__ bf1,
    const unsigned short* __restrict__ wf2tA, const float* __restrict__ bf2,
    const int* __restrict__ nbr, const float* __restrict__ y,
    float* __restrict__ agg)
{
    const int t = threadIdx.x;
    const int w = t >> 6, lane = t & 63, lr = lane & 15, lg = lane >> 4;
    const int atom = (blockIdx.x & 7) * 512 + (blockIdx.x >> 3);
    const int b = atom >> 9;

    __shared__ unsigned short s_h1[32 * FD];   // 8KB, swizzled [row][f] bf16
    __shared__ float s_r[NN], s_C[NN];
    __shared__ int   s_nb[NN];
    __shared__ float s_bf1[FD], s_bf2[FD];

    if (t < FD) { s_bf1[t] = bf1[t]; s_bf2[t] = bf2[t]; }

    int cnt;
    {
        const int k = lane;
        const int nb = nbr[atom * NN + k];
        const float m = nmask[atom * NN + k];
        const float* cb = cell + b * 9;
        const float* co = coff + (size_t)(atom * NN + k) * 3;
        const float ox = co[0]*cb[0] + co[1]*cb[3] + co[2]*cb[6];
        const float oy = co[0]*cb[1] + co[1]*cb[4] + co[2]*cb[7];
        const float oz = co[0]*cb[2] + co[1]*cb[5] + co[2]*cb[8];
        const float* pj = pos + (size_t)((b << 9) + nb) * 3;
        const float* pi = pos + (size_t)atom * 3;
        const float dx = pj[0] + ox - pi[0];
        const float dy = pj[1] + oy - pi[1];
        const float dz = pj[2] + oz - pi[2];
        const float d2 = dx*dx + dy*dy + dz*dz;
        const float r = sqrtf(m > 0.f ? d2 : 1.0f) * m;
        const float C = (r < 5.0f) ? m : 0.f;
        const bool act = (C != 0.f);
        const unsigned long long bal = __ballot(act);
        const int pre = __popcll(bal & ((1ull << k) - 1ull));
        cnt = __popcll(bal);
        if (act) { s_r[pre] = r; s_C[pre] = C; s_nb[pre] = nb; }
        if (k >= cnt) { s_r[k] = 1e20f; s_C[k] = 0.f; s_nb[k] = 0; }
    }
    const int Rt = (cnt + 15) >> 4;        // 16-row edge tiles
    const int nch = (Rt + 1) >> 1;         // chunks of <=2 tiles (s_h1 = 32 rows)

    const float DW = 5.0f / 24.0f;
    const float CO = -0.5f / (DW * DW);

    bf16x8 a1[4];
#pragma unroll
    for (int i = 0; i < 4; ++i)
        a1[i] = *(const bf16x8*)&wf1tA[((4 * w + i) * 64 + lane) * 8];

    f32x4 part[4] = {{0,0,0,0},{0,0,0,0},{0,0,0,0},{0,0,0,0}};

    for (int ch = 0; ch < nch; ++ch) {
        const int et0 = ch * 2;
        const int et1 = (et0 + 2 < Rt) ? et0 + 2 : Rt;
        if (ch) __syncthreads();           // prev chunk's phase 4 done

        // ---- phase 3: h1^T tiles -> LDS rows (et-et0)*16+lr ----
        for (int et = et0; et < et1; ++et) {
            const int edge = et * 16 + lr;
            const int row = (et - et0) * 16 + lr;
            const float re = s_r[edge];
            bf16x8 bfij;
#pragma unroll
            for (int e = 0; e < 8; ++e) {
                const int g = 8 * lg + e;
                float v = 0.f;
                if (g < GAUSS) { const float d = re - (float)g * DW; v = __expf(CO * d * d); }
                bfij[e] = (short)f2b(v);
            }
            const int exor = (row & 7) << 4;
#pragma unroll
            for (int i = 0; i < 4; ++i) {
                f32x4 acc = {0.f, 0.f, 0.f, 0.f};
                acc = __builtin_amdgcn_mfma_f32_16x16x32_bf16(a1[i], bfij, acc, 0, 0, 0);
                const int ft = 4 * w + i;
                const float4 b1 = *(const float4*)&s_bf1[ft * 16 + lg * 4];
                const unsigned int lo = (unsigned int)f2b(softplus_f(acc[0] + b1.x)) |
                                        ((unsigned int)f2b(softplus_f(acc[1] + b1.y)) << 16);
                const unsigned int hi = (unsigned int)f2b(softplus_f(acc[2] + b1.z)) |
                                        ((unsigned int)f2b(softplus_f(acc[3] + b1.w)) << 16);
                const int byte0 = row * 256 + (ft * 16 + lg * 4) * 2;
                *(uint2*)((char*)s_h1 + (byte0 ^ exor)) = make_uint2(lo, hi);
            }
        }
        __syncthreads();

        // ---- phase 4: j OUTER (a2f chunk-invariant), et inner ----
#pragma unroll
        for (int j = 0; j < 4; ++j) {
            bf16x8 a2f[4];
#pragma unroll
            for (int hs = 0; hs < 4; ++hs)
                a2f[hs] = *(const bf16x8*)&wf2tA[((hs * 8 + 4 * w + j) * 64 + lane) * 8];
            const int c0 = (4 * w + j) * 16 + lg * 4;
            const float4 b2 = *(const float4*)&s_bf2[c0];
            for (int et = et0; et < et1; ++et) {
                const int edge = et * 16 + lr;
                const int row = (et - et0) * 16 + lr;
                const int ebase = row * 256;
                const int exor = (row & 7) << 4;
                bf16x8 bh[4];
#pragma unroll
                for (int hs = 0; hs < 4; ++hs)
                    bh[hs] = *(const bf16x8*)((char*)s_h1 + ((ebase + hs * 64 + lg * 16) ^ exor));
                f32x4 acc = {0.f, 0.f, 0.f, 0.f};
#pragma unroll
                for (int hs = 0; hs < 4; ++hs)
                    acc = __builtin_amdgcn_mfma_f32_16x16x32_bf16(a2f[hs], bh[hs], acc, 0, 0, 0);
                const float Ce = s_C[edge];
                const float4 yv = *(const float4*)&y[(size_t)((b << 9) + s_nb[edge]) * FD + c0];
                part[j][0] += (acc[0] + b2.x) * Ce * yv.x;
                part[j][1] += (acc[1] + b2.y) * Ce * yv.y;
                part[j][2] += (acc[2] + b2.z) * Ce * yv.z;
                part[j][3] += (acc[3] + b2.w) * Ce * yv.w;
            }
        }
    }
#pragma unroll
    for (int j = 0; j < 4; ++j) {
#pragma unroll
        for (int m = 1; m <= 8; m <<= 1) {
            part[j][0] += __shfl_xor(part[j][0], m);
            part[j][1] += __shfl_xor(part[j][1], m);
            part[j][2] += __shfl_xor(part[j][2], m);
            part[j][3] += __shfl_xor(part[j][3], m);
        }
    }
    if (lr == 0) {
#pragma unroll
        for (int j = 0; j < 4; ++j) {
            const float4 o = {part[j][0], part[j][1], part[j][2], part[j][3]};
            *(float4*)&agg[(size_t)atom * FD + (4 * w + j) * 16 + lg * 4] = o;
        }
    }
}

// ---------------------------------------------------------------------------
// KC = post-MLP + gather inversion (R10 config).
// ---------------------------------------------------------------------------
__global__ __launch_bounds__(512) void kC_post_gather(
    const float* __restrict__ agg, const int* __restrict__ label,
    const unsigned short* __restrict__ wf2outB, const float* __restrict__ b_f2out,
    const unsigned short* __restrict__ wdenseB, const float* __restrict__ b_dense,
    float* __restrict__ out)
{
    const int t = threadIdx.x;
    const int w = t >> 6, lane = t & 63, lr = lane & 15, lg = lane >> 4;
    const int n0 = blockIdx.x * 16;
    const int b = n0 >> 9;
    __shared__ unsigned short s_t[16 * FD];   // 4KB

    const int src = (b << 9) + label[n0 + lr];
    bf16x8 a[4];
#pragma unroll
    for (int ks = 0; ks < 4; ++ks) {
        const float* p = &agg[(size_t)src * FD + ks * 32 + lg * 8];
        a[ks] = pack8(*(const float4*)p, *(const float4*)(p + 4));
    }
    const int ct = w;
    {
        f32x4 acc = {0.f, 0.f, 0.f, 0.f};
#pragma unroll
        for (int ks = 0; ks < 4; ++ks)
            acc = __builtin_amdgcn_mfma_f32_16x16x32_bf16(
                a[ks], *(const bf16x8*)&wf2outB[((ks * 8 + ct) * 64 + lane) * 8],
                acc, 0, 0, 0);
        const int col = ct * 16 + lr;
        const float bias = b_f2out[col];
#pragma unroll
        for (int r = 0; r < 4; ++r) {
            const int row = lg * 4 + r;
            *(unsigned short*)((char*)s_t + ((row * 256 + col * 2) ^ ((row & 7) << 4)))
                = f2b(softplus_f(acc[r] + bias));
        }
    }
    __syncthreads();
    bf16x8 a2[4];
#pragma unroll
    for (int ks = 0; ks < 4; ++ks)
        a2[ks] = *(const bf16x8*)((char*)s_t +
                 ((lr * 256 + (ks * 32 + lg * 8) * 2) ^ ((lr & 7) << 4)));
    {
        f32x4 acc = {0.f, 0.f, 0.f, 0.f};
#pragma unroll
        for (int ks = 0; ks < 4; ++ks)
            acc = __builtin_amdgcn_mfma_f32_16x16x32_bf16(
                a2[ks], *(const bf16x8*)&wdenseB[((ks * 8 + ct) * 64 + lane) * 8],
                acc, 0, 0, 0);
        const int col = ct * 16 + lr;
        const float bias = b_dense[col];
#pragma unroll
        for (int r = 0; r < 4; ++r)
            out[(size_t)(n0 + lg * 4 + r) * 256 + FD + col] = acc[r] + bias;
    }
}

extern "C" void kernel_launch(void* const* d_in, const int* in_sizes, int n_in,
                              void* d_out, int out_size, void* d_ws, size_t ws_size,
                              hipStream_t stream)
{
    const float* positions = (const float*)d_in[0];
    const float* cell      = (const float*)d_in[1];
    const float* coff      = (const float*)d_in[2];
    const float* nmask     = (const float*)d_in[3];
    const float* emb       = (const float*)d_in[4];
    const float* wf1       = (const float*)d_in[5];
    const float* bf1       = (const float*)d_in[6];
    const float* wf2       = (const float*)d_in[7];
    const float* bf2       = (const float*)d_in[8];
    const float* w_in2f    = (const float*)d_in[9];
    const float* w_f2out   = (const float*)d_in[10];
    const float* b_f2out   = (const float*)d_in[11];
    const float* w_dense   = (const float*)d_in[12];
    const float* b_dense   = (const float*)d_in[13];
    const int*   zn        = (const int*)d_in[14];
    const int*   nbr       = (const int*)d_in[15];
    const int*   label     = (const int*)d_in[16];

    float* out = (float*)d_out;
    float* ws  = (float*)d_ws;
    float* y   = ws;                       // [4096,128]
    float* agg = ws + BN * FD;             // [4096,128]
    unsigned short* wf1tA   = (unsigned short*)(ws + 2 * BN * FD);  // 4096
    unsigned short* wf2tA   = wf1tA + 4096;                         // 16384
    unsigned short* wf2outB = wf2tA + 16384;                        // 16384
    unsigned short* wdenseB = wf2outB + 16384;                      // 16384

    hipLaunchKernelGGL(kA_prep_embed_y, dim3(BN / 16), dim3(512), 0, stream,
                       emb, zn, wf1, wf2, w_in2f, w_f2out, w_dense,
                       wf1tA, wf2tA, wf2outB, wdenseB, y, out);
    hipLaunchKernelGGL(kB_conv, dim3(BN), dim3(128), 0, stream,
                       positions, cell, coff, nmask, wf1tA, bf1, wf2tA, bf2,
                       nbr, y, agg);
    hipLaunchKernelGGL(kC_post_gather, dim3(BN / 16), dim3(512), 0, stream,
                       agg, label, wf2outB, b_f2out, wdenseB, b_dense, out);
}

// Round 18
// 41.745 us; speedup vs baseline: 2.1360x; 2.1360x over previous
//
#include <hip/hip_runtime.h>
#include <cmath>

#define BN 4096      // B*N
#define NN 64
#define GAUSS 25
#define FD 128

typedef __attribute__((ext_vector_type(8))) short bf16x8;
typedef __attribute__((ext_vector_type(4))) float f32x4;

__device__ __forceinline__ float softplus_f(float x) {
    const float t = __expf(-fabsf(x));
    return fmaxf(x, 0.f) + __logf(1.f + t);
}
// 4-op RNE emulation (R10-proven; ROCm's __float2bfloat16 adds NaN cmp/cndmask)
__device__ __forceinline__ unsigned short f2b(float f) {
    unsigned int u = __float_as_uint(f);
    unsigned int r = (u + 0x7FFFu + ((u >> 16) & 1u)) >> 16;
    return (unsigned short)r;
}
__device__ __forceinline__ bf16x8 pack8(const float4 p0, const float4 p1) {
    bf16x8 r;
    r[0] = (short)f2b(p0.x); r[1] = (short)f2b(p0.y);
    r[2] = (short)f2b(p0.z); r[3] = (short)f2b(p0.w);
    r[4] = (short)f2b(p1.x); r[5] = (short)f2b(p1.y);
    r[6] = (short)f2b(p1.z); r[7] = (short)f2b(p1.w);
    return r;
}

// ---------------------------------------------------------------------------
// KA = k0 + k1 fused (R10/R16 config).  Grid 256 x 512.
// ---------------------------------------------------------------------------
__global__ __launch_bounds__(512) void kA_prep_embed_y(
    const float* __restrict__ emb, const int* __restrict__ zn,
    const float* __restrict__ wf1, const float* __restrict__ wf2,
    const float* __restrict__ w_in2f, const float* __restrict__ w_f2out,
    const float* __restrict__ w_dense,
    unsigned short* __restrict__ wf1tA, unsigned short* __restrict__ wf2tA,
    unsigned short* __restrict__ wf2outB, unsigned short* __restrict__ wdenseB,
    float* __restrict__ y, float* __restrict__ out)
{
    const int t = threadIdx.x;
    const int w = t >> 6, lane = t & 63, lr = lane & 15, lg = lane >> 4;
    __shared__ unsigned short s_w[16384];   // 32KB: win2fB frags

    // ---- 0a: pack global frag arrays for KB / KC ----
    {
        const int idx = blockIdx.x * 512 + t;
        if (idx < 4096) {
            const int e = idx & 7, l = (idx >> 3) & 63, ft = idx >> 9;
            const int f = ft * 16 + (l & 15);
            const int g = 8 * (l >> 4) + e;
            wf1tA[idx] = (g < GAUSS) ? f2b(wf1[g * FD + f]) : (unsigned short)0;
        } else if (idx < 20480) {
            const int i = idx - 4096;
            const int e = i & 7, l = (i >> 3) & 63, ct = (i >> 9) & 7, ks = i >> 12;
            wf2tA[i] = f2b(wf2[(ks * 32 + 8 * (l >> 4) + e) * FD + ct * 16 + (l & 15)]);
        } else if (idx < 36864) {
            const int i = idx - 20480;
            const int e = i & 7, l = (i >> 3) & 63, ct = (i >> 9) & 7, ks = i >> 12;
            wf2outB[i] = f2b(w_f2out[(ks * 32 + 8 * (l >> 4) + e) * FD + ct * 16 + (l & 15)]);
        } else if (idx < 53248) {
            const int i = idx - 36864;
            const int e = i & 7, l = (i >> 3) & 63, ct = (i >> 9) & 7, ks = i >> 12;
            wdenseB[i] = f2b(w_dense[(ks * 32 + 8 * (l >> 4) + e) * FD + ct * 16 + (l & 15)]);
        }
    }
    // ---- 0b: pack win2fB into LDS (each thread 32 consecutive slots) ----
    for (int i = t * 32, end = t * 32 + 32; i < end; ++i) {
        const int e = i & 7, l = (i >> 3) & 63, ct = (i >> 9) & 7, ks = i >> 12;
        const int col = ct * 16 + (l & 15);
        const int k = ks * 32 + 8 * (l >> 4) + e;
        s_w[i] = f2b(w_in2f[k * FD + col]);
    }
    __syncthreads();

    // ---- 1: embed + out-write + y MFMA ----
    const int atom0 = blockIdx.x * 16;
    const int atom = atom0 + lr;
    const int z = zn[atom];
    const float* xrow = emb + (size_t)z * FD;
    bf16x8 a[4];
#pragma unroll
    for (int ks = 0; ks < 4; ++ks) {
        const int c0 = ks * 32 + lg * 8;
        const float4 p0 = *(const float4*)&xrow[c0];
        const float4 p1 = *(const float4*)&xrow[c0 + 4];
        if (w == 0) {
            *(float4*)&out[(size_t)atom * 256 + c0] = p0;
            *(float4*)&out[(size_t)atom * 256 + c0 + 4] = p1;
        }
        a[ks] = pack8(p0, p1);
    }
    f32x4 acc = {0.f, 0.f, 0.f, 0.f};
#pragma unroll
    for (int ks = 0; ks < 4; ++ks)
        acc = __builtin_amdgcn_mfma_f32_16x16x32_bf16(
            a[ks], *(const bf16x8*)&s_w[((ks * 8 + w) * 64 + lane) * 8],
            acc, 0, 0, 0);
    const int col = w * 16 + lr;
#pragma unroll
    for (int r = 0; r < 4; ++r)
        y[(size_t)(atom0 + lg * 4 + r) * FD + col] = acc[r];
}

// ---------------------------------------------------------------------------
// KB: continuous-filter conv. R16 base (64-row s_h1, (128,4), j-outer) +
// ONE change: y-row fragments for edge-tiles 0..1 PREFETCHED right after
// phase 1 (T14 issue-early) so their L2 latency hides under phase 3's
// exp/softplus chains; phase 4's first two edge-tiles statically unrolled
// (static yv indexing, rule #20). Rare Rt>2 falls back to inline loads.
// ---------------------------------------------------------------------------
#define KB_P4_BODY(JJ, EDGE, YV)                                              \
    {                                                                         \
        const int ebase_ = (EDGE) * 256;                                      \
        const int exor_ = ((EDGE) & 7) << 4;                                  \
        bf16x8 bh_[4];                                                        \
        _Pragma("unroll")                                                     \
        for (int hs = 0; hs < 4; ++hs)                                        \
            bh_[hs] = *(const bf16x8*)((char*)s_h1 +                          \
                      ((ebase_ + hs * 64 + lg * 16) ^ exor_));                \
        f32x4 acc_ = {0.f, 0.f, 0.f, 0.f};                                    \
        _Pragma("unroll")                                                     \
        for (int hs = 0; hs < 4; ++hs)                                        \
            acc_ = __builtin_amdgcn_mfma_f32_16x16x32_bf16(a2f[hs], bh_[hs],  \
                                                           acc_, 0, 0, 0);    \
        const float Ce_ = s_C[(EDGE)];                                        \
        part[JJ][0] += (acc_[0] + b2.x) * Ce_ * (YV).x;                       \
        part[JJ][1] += (acc_[1] + b2.y) * Ce_ * (YV).y;                       \
        part[JJ][2] += (acc_[2] + b2.z) * Ce_ * (YV).z;                       \
        part[JJ][3] += (acc_[3] + b2.w) * Ce_ * (YV).w;                       \
    }

__global__ __launch_bounds__(128, 4) void kB_conv(
    const float* __restrict__ pos, const float* __restrict__ cell,
    const float* __restrict__ coff, const float* __restrict__ nmask,
    const unsigned short* __restrict__ wf1tA, const float* __restrict__ bf1,
    const unsigned short* __restrict__ wf2tA, const float* __restrict__ bf2,
    const int* __restrict__ nbr, const float* __restrict__ y,
    float* __restrict__ agg)
{
    const int t = threadIdx.x;
    const int w = t >> 6, lane = t & 63, lr = lane & 15, lg = lane >> 4;
    const int atom = (blockIdx.x & 7) * 512 + (blockIdx.x >> 3);
    const int b = atom >> 9;

    __shared__ unsigned short s_h1[NN * FD];   // 16KB, swizzled [edge][f] bf16
    __shared__ float s_r[NN], s_C[NN];
    __shared__ int   s_nb[NN];
    __shared__ float s_bf1[FD], s_bf2[FD];

    if (t < FD) { s_bf1[t] = bf1[t]; s_bf2[t] = bf2[t]; }

    bf16x8 a1[4];
#pragma unroll
    for (int i = 0; i < 4; ++i)
        a1[i] = *(const bf16x8*)&wf1tA[((4 * w + i) * 64 + lane) * 8];

    int cnt;
    {
        const int k = lane;
        const int nb = nbr[atom * NN + k];
        const float m = nmask[atom * NN + k];
        const float* cb = cell + b * 9;
        const float* co = coff + (size_t)(atom * NN + k) * 3;
        const float ox = co[0]*cb[0] + co[1]*cb[3] + co[2]*cb[6];
        const float oy = co[0]*cb[1] + co[1]*cb[4] + co[2]*cb[7];
        const float oz = co[0]*cb[2] + co[1]*cb[5] + co[2]*cb[8];
        const float* pj = pos + (size_t)((b << 9) + nb) * 3;
        const float* pi = pos + (size_t)atom * 3;
        const float dx = pj[0] + ox - pi[0];
        const float dy = pj[1] + oy - pi[1];
        const float dz = pj[2] + oz - pi[2];
        const float d2 = dx*dx + dy*dy + dz*dz;
        const float r = sqrtf(m > 0.f ? d2 : 1.0f) * m;
        const float C = (r < 5.0f) ? m : 0.f;
        const bool act = (C != 0.f);
        const unsigned long long bal = __ballot(act);
        const int pre = __popcll(bal & ((1ull << k) - 1ull));
        cnt = __popcll(bal);
        if (act) { s_r[pre] = r; s_C[pre] = C; s_nb[pre] = nb; }
        if (k >= cnt) { s_r[k] = 1e20f; s_C[k] = 0.f; s_nb[k] = 0; }
    }
    const int Rt = (cnt + 15) >> 4;

    // ---- T14 prefetch: y rows for edge-tiles 0..1, issued BEFORE phase 3
    //      so L2 latency hides under the exp/softplus chains ----
    float4 yv0[4], yv1[4];
    {
        const float* r0 = y + (size_t)((b << 9) + s_nb[lr]) * FD;
        const float* r1 = y + (size_t)((b << 9) + s_nb[16 + lr]) * FD;
#pragma unroll
        for (int j = 0; j < 4; ++j) {
            const int c0 = (4 * w + j) * 16 + lg * 4;
            yv0[j] = *(const float4*)&r0[c0];
            yv1[j] = *(const float4*)&r1[c0];
        }
    }

    const float DW = 5.0f / 24.0f;
    const float CO = -0.5f / (DW * DW);

    for (int et = 0; et < Rt; ++et) {
        const int edge = et * 16 + lr;
        const float re = s_r[edge];
        bf16x8 bfij;
#pragma unroll
        for (int e = 0; e < 8; ++e) {
            const int g = 8 * lg + e;
            float v = 0.f;
            if (g < GAUSS) { const float d = re - (float)g * DW; v = __expf(CO * d * d); }
            bfij[e] = (short)f2b(v);
        }
        const int exor = (edge & 7) << 4;
#pragma unroll
        for (int i = 0; i < 4; ++i) {
            f32x4 acc = {0.f, 0.f, 0.f, 0.f};
            acc = __builtin_amdgcn_mfma_f32_16x16x32_bf16(a1[i], bfij, acc, 0, 0, 0);
            const int ft = 4 * w + i;
            const float4 b1 = *(const float4*)&s_bf1[ft * 16 + lg * 4];
            const unsigned int lo = (unsigned int)f2b(softplus_f(acc[0] + b1.x)) |
                                    ((unsigned int)f2b(softplus_f(acc[1] + b1.y)) << 16);
            const unsigned int hi = (unsigned int)f2b(softplus_f(acc[2] + b1.z)) |
                                    ((unsigned int)f2b(softplus_f(acc[3] + b1.w)) << 16);
            const int byte0 = edge * 256 + (ft * 16 + lg * 4) * 2;
            *(uint2*)((char*)s_h1 + (byte0 ^ exor)) = make_uint2(lo, hi);
        }
    }
    __syncthreads();

    // ---- phase 4: j OUTER; first two edge-tiles statically unrolled ----
    f32x4 part[4] = {{0,0,0,0},{0,0,0,0},{0,0,0,0},{0,0,0,0}};
#pragma unroll
    for (int j = 0; j < 4; ++j) {
        bf16x8 a2f[4];
#pragma unroll
        for (int hs = 0; hs < 4; ++hs)
            a2f[hs] = *(const bf16x8*)&wf2tA[((hs * 8 + 4 * w + j) * 64 + lane) * 8];
        const int c0 = (4 * w + j) * 16 + lg * 4;
        const float4 b2 = *(const float4*)&s_bf2[c0];
        if (Rt > 0) KB_P4_BODY(j, lr, yv0[j]);
        if (Rt > 1) KB_P4_BODY(j, 16 + lr, yv1[j]);
        for (int et = 2; et < Rt; ++et) {           // rare (cnt > 32)
            const int edge = et * 16 + lr;
            const float4 yvx = *(const float4*)&y[(size_t)((b << 9) + s_nb[edge]) * FD + c0];
            KB_P4_BODY(j, edge, yvx);
        }
    }
#pragma unroll
    for (int j = 0; j < 4; ++j) {
#pragma unroll
        for (int m = 1; m <= 8; m <<= 1) {
            part[j][0] += __shfl_xor(part[j][0], m);
            part[j][1] += __shfl_xor(part[j][1], m);
            part[j][2] += __shfl_xor(part[j][2], m);
            part[j][3] += __shfl_xor(part[j][3], m);
        }
    }
    if (lr == 0) {
#pragma unroll
        for (int j = 0; j < 4; ++j) {
            const float4 o = {part[j][0], part[j][1], part[j][2], part[j][3]};
            *(float4*)&agg[(size_t)atom * FD + (4 * w + j) * 16 + lg * 4] = o;
        }
    }
}

// ---------------------------------------------------------------------------
// KC = post-MLP + gather inversion (R10/R16 config).
// ---------------------------------------------------------------------------
__global__ __launch_bounds__(512) void kC_post_gather(
    const float* __restrict__ agg, const int* __restrict__ label,
    const unsigned short* __restrict__ wf2outB, const float* __restrict__ b_f2out,
    const unsigned short* __restrict__ wdenseB, const float* __restrict__ b_dense,
    float* __restrict__ out)
{
    const int t = threadIdx.x;
    const int w = t >> 6, lane = t & 63, lr = lane & 15, lg = lane >> 4;
    const int n0 = blockIdx.x * 16;
    const int b = n0 >> 9;
    __shared__ unsigned short s_t[16 * FD];   // 4KB

    const int src = (b << 9) + label[n0 + lr];
    bf16x8 a[4];
#pragma unroll
    for (int ks = 0; ks < 4; ++ks) {
        const float* p = &agg[(size_t)src * FD + ks * 32 + lg * 8];
        a[ks] = pack8(*(const float4*)p, *(const float4*)(p + 4));
    }
    const int ct = w;
    {
        f32x4 acc = {0.f, 0.f, 0.f, 0.f};
#pragma unroll
        for (int ks = 0; ks < 4; ++ks)
            acc = __builtin_amdgcn_mfma_f32_16x16x32_bf16(
                a[ks], *(const bf16x8*)&wf2outB[((ks * 8 + ct) * 64 + lane) * 8],
                acc, 0, 0, 0);
        const int col = ct * 16 + lr;
        const float bias = b_f2out[col];
#pragma unroll
        for (int r = 0; r < 4; ++r) {
            const int row = lg * 4 + r;
            *(unsigned short*)((char*)s_t + ((row * 256 + col * 2) ^ ((row & 7) << 4)))
                = f2b(softplus_f(acc[r] + bias));
        }
    }
    __syncthreads();
    bf16x8 a2[4];
#pragma unroll
    for (int ks = 0; ks < 4; ++ks)
        a2[ks] = *(const bf16x8*)((char*)s_t +
                 ((lr * 256 + (ks * 32 + lg * 8) * 2) ^ ((lr & 7) << 4)));
    {
        f32x4 acc = {0.f, 0.f, 0.f, 0.f};
#pragma unroll
        for (int ks = 0; ks < 4; ++ks)
            acc = __builtin_amdgcn_mfma_f32_16x16x32_bf16(
                a2[ks], *(const bf16x8*)&wdenseB[((ks * 8 + ct) * 64 + lane) * 8],
                acc, 0, 0, 0);
        const int col = ct * 16 + lr;
        const float bias = b_dense[col];
#pragma unroll
        for (int r = 0; r < 4; ++r)
            out[(size_t)(n0 + lg * 4 + r) * 256 + FD + col] = acc[r] + bias;
    }
}

extern "C" void kernel_launch(void* const* d_in, const int* in_sizes, int n_in,
                              void* d_out, int out_size, void* d_ws, size_t ws_size,
                              hipStream_t stream)
{
    const float* positions = (const float*)d_in[0];
    const float* cell      = (const float*)d_in[1];
    const float* coff      = (const float*)d_in[2];
    const float* nmask     = (const float*)d_in[3];
    const float* emb       = (const float*)d_in[4];
    const float* wf1       = (const float*)d_in[5];
    const float* bf1       = (const float*)d_in[6];
    const float* wf2       = (const float*)d_in[7];
    const float* bf2       = (const float*)d_in[8];
    const float* w_in2f    = (const float*)d_in[9];
    const float* w_f2out   = (const float*)d_in[10];
    const float* b_f2out   = (const float*)d_in[11];
    const float* w_dense   = (const float*)d_in[12];
    const float* b_dense   = (const float*)d_in[13];
    const int*   zn        = (const int*)d_in[14];
    const int*   nbr       = (const int*)d_in[15];
    const int*   label     = (const int*)d_in[16];

    float* out = (float*)d_out;
    float* ws  = (float*)d_ws;
    float* y   = ws;                       // [4096,128]
    float* agg = ws + BN * FD;             // [4096,128]
    unsigned short* wf1tA   = (unsigned short*)(ws + 2 * BN * FD);  // 4096
    unsigned short* wf2tA   = wf1tA + 4096;                         // 16384
    unsigned short* wf2outB = wf2tA + 16384;                        // 16384
    unsigned short* wdenseB = wf2outB + 16384;                      // 16384

    hipLaunchKernelGGL(kA_prep_embed_y, dim3(BN / 16), dim3(512), 0, stream,
                       emb, zn, wf1, wf2, w_in2f, w_f2out, w_dense,
                       wf1tA, wf2tA, wf2outB, wdenseB, y, out);
    hipLaunchKernelGGL(kB_conv, dim3(BN), dim3(128), 0, stream,
                       positions, cell, coff, nmask, wf1tA, bf1, wf2tA, bf2,
                       nbr, y, agg);
    hipLaunchKernelGGL(kC_post_gather, dim3(BN / 16), dim3(512), 0, stream,
                       agg, label, wf2outB, b_f2out, wdenseB, b_dense, out);
}

// Round 19
// 38.218 us; speedup vs baseline: 2.3332x; 1.0923x over previous
//
#include <hip/hip_runtime.h>
#include <cmath>

#define BN 4096      // B*N
#define NN 64
#define GAUSS 25
#define FD 128

typedef __attribute__((ext_vector_type(8))) short bf16x8;
typedef __attribute__((ext_vector_type(4))) float f32x4;

__device__ __forceinline__ float softplus_f(float x) {
    const float t = __expf(-fabsf(x));
    return fmaxf(x, 0.f) + __logf(1.f + t);
}
// 4-op RNE emulation (R10-proven; ROCm's __float2bfloat16 adds NaN cmp/cndmask)
__device__ __forceinline__ unsigned short f2b(float f) {
    unsigned int u = __float_as_uint(f);
    unsigned int r = (u + 0x7FFFu + ((u >> 16) & 1u)) >> 16;
    return (unsigned short)r;
}
__device__ __forceinline__ bf16x8 pack8(const float4 p0, const float4 p1) {
    bf16x8 r;
    r[0] = (short)f2b(p0.x); r[1] = (short)f2b(p0.y);
    r[2] = (short)f2b(p0.z); r[3] = (short)f2b(p0.w);
    r[4] = (short)f2b(p1.x); r[5] = (short)f2b(p1.y);
    r[6] = (short)f2b(p1.z); r[7] = (short)f2b(p1.w);
    return r;
}

// ---------------------------------------------------------------------------
// KA = k0 + k1 fused (R10/R16 config).  Grid 256 x 512.
// ---------------------------------------------------------------------------
__global__ __launch_bounds__(512) void kA_prep_embed_y(
    const float* __restrict__ emb, const int* __restrict__ zn,
    const float* __restrict__ wf1, const float* __restrict__ wf2,
    const float* __restrict__ w_in2f, const float* __restrict__ w_f2out,
    const float* __restrict__ w_dense,
    unsigned short* __restrict__ wf1tA, unsigned short* __restrict__ wf2tA,
    unsigned short* __restrict__ wf2outB, unsigned short* __restrict__ wdenseB,
    float* __restrict__ y, float* __restrict__ out)
{
    const int t = threadIdx.x;
    const int w = t >> 6, lane = t & 63, lr = lane & 15, lg = lane >> 4;
    __shared__ unsigned short s_w[16384];   // 32KB: win2fB frags

    // ---- 0a: pack global frag arrays for KB / KC ----
    {
        const int idx = blockIdx.x * 512 + t;
        if (idx < 4096) {
            const int e = idx & 7, l = (idx >> 3) & 63, ft = idx >> 9;
            const int f = ft * 16 + (l & 15);
            const int g = 8 * (l >> 4) + e;
            wf1tA[idx] = (g < GAUSS) ? f2b(wf1[g * FD + f]) : (unsigned short)0;
        } else if (idx < 20480) {
            const int i = idx - 4096;
            const int e = i & 7, l = (i >> 3) & 63, ct = (i >> 9) & 7, ks = i >> 12;
            wf2tA[i] = f2b(wf2[(ks * 32 + 8 * (l >> 4) + e) * FD + ct * 16 + (l & 15)]);
        } else if (idx < 36864) {
            const int i = idx - 20480;
            const int e = i & 7, l = (i >> 3) & 63, ct = (i >> 9) & 7, ks = i >> 12;
            wf2outB[i] = f2b(w_f2out[(ks * 32 + 8 * (l >> 4) + e) * FD + ct * 16 + (l & 15)]);
        } else if (idx < 53248) {
            const int i = idx - 36864;
            const int e = i & 7, l = (i >> 3) & 63, ct = (i >> 9) & 7, ks = i >> 12;
            wdenseB[i] = f2b(w_dense[(ks * 32 + 8 * (l >> 4) + e) * FD + ct * 16 + (l & 15)]);
        }
    }
    // ---- 0b: pack win2fB into LDS (each thread 32 consecutive slots) ----
    for (int i = t * 32, end = t * 32 + 32; i < end; ++i) {
        const int e = i & 7, l = (i >> 3) & 63, ct = (i >> 9) & 7, ks = i >> 12;
        const int col = ct * 16 + (l & 15);
        const int k = ks * 32 + 8 * (l >> 4) + e;
        s_w[i] = f2b(w_in2f[k * FD + col]);
    }
    __syncthreads();

    // ---- 1: embed + out-write + y MFMA ----
    const int atom0 = blockIdx.x * 16;
    const int atom = atom0 + lr;
    const int z = zn[atom];
    const float* xrow = emb + (size_t)z * FD;
    bf16x8 a[4];
#pragma unroll
    for (int ks = 0; ks < 4; ++ks) {
        const int c0 = ks * 32 + lg * 8;
        const float4 p0 = *(const float4*)&xrow[c0];
        const float4 p1 = *(const float4*)&xrow[c0 + 4];
        if (w == 0) {
            *(float4*)&out[(size_t)atom * 256 + c0] = p0;
            *(float4*)&out[(size_t)atom * 256 + c0 + 4] = p1;
        }
        a[ks] = pack8(p0, p1);
    }
    f32x4 acc = {0.f, 0.f, 0.f, 0.f};
#pragma unroll
    for (int ks = 0; ks < 4; ++ks)
        acc = __builtin_amdgcn_mfma_f32_16x16x32_bf16(
            a[ks], *(const bf16x8*)&s_w[((ks * 8 + w) * 64 + lane) * 8],
            acc, 0, 0, 0);
    const int col = w * 16 + lr;
#pragma unroll
    for (int r = 0; r < 4; ++r)
        y[(size_t)(atom0 + lg * 4 + r) * FD + col] = acc[r];
}

// ---------------------------------------------------------------------------
// KB: continuous-filter conv. R16 base, ONE structural change: FOUR waves
// per atom (256 threads) — wave w owns column-tiles {2w, 2w+1} in both
// phases, halving each wave's phase-3/4 work and the per-block critical
// path. Phase 1 redundant per wave (own-wave LDS ordering); one extra
// barrier covers the cross-wave bias staging.
// ---------------------------------------------------------------------------
__global__ __launch_bounds__(256, 4) void kB_conv(
    const float* __restrict__ pos, const float* __restrict__ cell,
    const float* __restrict__ coff, const float* __restrict__ nmask,
    const unsigned short* __restrict__ wf1tA, const float* __restrict__ bf1,
    const unsigned short* __restrict__ wf2tA, const float* __restrict__ bf2,
    const int* __restrict__ nbr, const float* __restrict__ y,
    float* __restrict__ agg)
{
    const int t = threadIdx.x;
    const int w = t >> 6, lane = t & 63, lr = lane & 15, lg = lane >> 4;
    const int atom = (blockIdx.x & 7) * 512 + (blockIdx.x >> 3);
    const int b = atom >> 9;

    __shared__ unsigned short s_h1[NN * FD];   // 16KB, swizzled [edge][f] bf16
    __shared__ float s_r[NN], s_C[NN];
    __shared__ int   s_nb[NN];
    __shared__ float s_bf1[FD], s_bf2[FD];

    if (t < FD) s_bf1[t] = bf1[t];
    else        s_bf2[t - FD] = bf2[t - FD];

    bf16x8 a1[2];
#pragma unroll
    for (int i = 0; i < 2; ++i)
        a1[i] = *(const bf16x8*)&wf1tA[((2 * w + i) * 64 + lane) * 8];

    int cnt;
    {
        const int k = lane;
        const int nb = nbr[atom * NN + k];
        const float m = nmask[atom * NN + k];
        const float* cb = cell + b * 9;
        const float* co = coff + (size_t)(atom * NN + k) * 3;
        const float ox = co[0]*cb[0] + co[1]*cb[3] + co[2]*cb[6];
        const float oy = co[0]*cb[1] + co[1]*cb[4] + co[2]*cb[7];
        const float oz = co[0]*cb[2] + co[1]*cb[5] + co[2]*cb[8];
        const float* pj = pos + (size_t)((b << 9) + nb) * 3;
        const float* pi = pos + (size_t)atom * 3;
        const float dx = pj[0] + ox - pi[0];
        const float dy = pj[1] + oy - pi[1];
        const float dz = pj[2] + oz - pi[2];
        const float d2 = dx*dx + dy*dy + dz*dz;
        const float r = sqrtf(m > 0.f ? d2 : 1.0f) * m;
        const float C = (r < 5.0f) ? m : 0.f;
        const bool act = (C != 0.f);
        const unsigned long long bal = __ballot(act);
        const int pre = __popcll(bal & ((1ull << k) - 1ull));
        cnt = __popcll(bal);
        if (act) { s_r[pre] = r; s_C[pre] = C; s_nb[pre] = nb; }
        if (k >= cnt) { s_r[k] = 1e20f; s_C[k] = 0.f; s_nb[k] = 0; }
    }
    __syncthreads();   // bias staging crosses waves (s_r/C/nb are per-wave redundant)

    const int Rt = (cnt + 15) >> 4;

    const float DW = 5.0f / 24.0f;
    const float CO = -0.5f / (DW * DW);

    // ---- phase 3: h1^T tiles -> LDS (each wave its 2 f-tiles) ----
    for (int et = 0; et < Rt; ++et) {
        const int edge = et * 16 + lr;
        const float re = s_r[edge];
        bf16x8 bfij;
#pragma unroll
        for (int e = 0; e < 8; ++e) {
            const int g = 8 * lg + e;
            float v = 0.f;
            if (g < GAUSS) { const float d = re - (float)g * DW; v = __expf(CO * d * d); }
            bfij[e] = (short)f2b(v);
        }
        const int exor = (edge & 7) << 4;
#pragma unroll
        for (int i = 0; i < 2; ++i) {
            f32x4 acc = {0.f, 0.f, 0.f, 0.f};
            acc = __builtin_amdgcn_mfma_f32_16x16x32_bf16(a1[i], bfij, acc, 0, 0, 0);
            const int ft = 2 * w + i;
            const float4 b1 = *(const float4*)&s_bf1[ft * 16 + lg * 4];
            const unsigned int lo = (unsigned int)f2b(softplus_f(acc[0] + b1.x)) |
                                    ((unsigned int)f2b(softplus_f(acc[1] + b1.y)) << 16);
            const unsigned int hi = (unsigned int)f2b(softplus_f(acc[2] + b1.z)) |
                                    ((unsigned int)f2b(softplus_f(acc[3] + b1.w)) << 16);
            const int byte0 = edge * 256 + (ft * 16 + lg * 4) * 2;
            *(uint2*)((char*)s_h1 + (byte0 ^ exor)) = make_uint2(lo, hi);
        }
    }
    __syncthreads();   // h1 handoff

    // ---- phase 4: j OUTER (a2f et-invariant), et inner ----
    f32x4 part[2] = {{0,0,0,0},{0,0,0,0}};
#pragma unroll
    for (int j = 0; j < 2; ++j) {
        bf16x8 a2f[4];
#pragma unroll
        for (int hs = 0; hs < 4; ++hs)
            a2f[hs] = *(const bf16x8*)&wf2tA[((hs * 8 + 2 * w + j) * 64 + lane) * 8];
        const int c0 = (2 * w + j) * 16 + lg * 4;
        const float4 b2 = *(const float4*)&s_bf2[c0];
        for (int et = 0; et < Rt; ++et) {
            const int edge = et * 16 + lr;
            const int ebase = edge * 256;
            const int exor = (edge & 7) << 4;
            bf16x8 bh[4];
#pragma unroll
            for (int hs = 0; hs < 4; ++hs)
                bh[hs] = *(const bf16x8*)((char*)s_h1 + ((ebase + hs * 64 + lg * 16) ^ exor));
            f32x4 acc = {0.f, 0.f, 0.f, 0.f};
#pragma unroll
            for (int hs = 0; hs < 4; ++hs)
                acc = __builtin_amdgcn_mfma_f32_16x16x32_bf16(a2f[hs], bh[hs], acc, 0, 0, 0);
            const float Ce = s_C[edge];
            const float4 yv = *(const float4*)&y[(size_t)((b << 9) + s_nb[edge]) * FD + c0];
            part[j][0] += (acc[0] + b2.x) * Ce * yv.x;
            part[j][1] += (acc[1] + b2.y) * Ce * yv.y;
            part[j][2] += (acc[2] + b2.z) * Ce * yv.z;
            part[j][3] += (acc[3] + b2.w) * Ce * yv.w;
        }
    }
#pragma unroll
    for (int j = 0; j < 2; ++j) {
#pragma unroll
        for (int m = 1; m <= 8; m <<= 1) {
            part[j][0] += __shfl_xor(part[j][0], m);
            part[j][1] += __shfl_xor(part[j][1], m);
            part[j][2] += __shfl_xor(part[j][2], m);
            part[j][3] += __shfl_xor(part[j][3], m);
        }
    }
    if (lr == 0) {
#pragma unroll
        for (int j = 0; j < 2; ++j) {
            const float4 o = {part[j][0], part[j][1], part[j][2], part[j][3]};
            *(float4*)&agg[(size_t)atom * FD + (2 * w + j) * 16 + lg * 4] = o;
        }
    }
}

// ---------------------------------------------------------------------------
// KC = post-MLP + gather inversion (R10/R16 config).
// ---------------------------------------------------------------------------
__global__ __launch_bounds__(512) void kC_post_gather(
    const float* __restrict__ agg, const int* __restrict__ label,
    const unsigned short* __restrict__ wf2outB, const float* __restrict__ b_f2out,
    const unsigned short* __restrict__ wdenseB, const float* __restrict__ b_dense,
    float* __restrict__ out)
{
    const int t = threadIdx.x;
    const int w = t >> 6, lane = t & 63, lr = lane & 15, lg = lane >> 4;
    const int n0 = blockIdx.x * 16;
    const int b = n0 >> 9;
    __shared__ unsigned short s_t[16 * FD];   // 4KB

    const int src = (b << 9) + label[n0 + lr];
    bf16x8 a[4];
#pragma unroll
    for (int ks = 0; ks < 4; ++ks) {
        const float* p = &agg[(size_t)src * FD + ks * 32 + lg * 8];
        a[ks] = pack8(*(const float4*)p, *(const float4*)(p + 4));
    }
    const int ct = w;
    {
        f32x4 acc = {0.f, 0.f, 0.f, 0.f};
#pragma unroll
        for (int ks = 0; ks < 4; ++ks)
            acc = __builtin_amdgcn_mfma_f32_16x16x32_bf16(
                a[ks], *(const bf16x8*)&wf2outB[((ks * 8 + ct) * 64 + lane) * 8],
                acc, 0, 0, 0);
        const int col = ct * 16 + lr;
        const float bias = b_f2out[col];
#pragma unroll
        for (int r = 0; r < 4; ++r) {
            const int row = lg * 4 + r;
            *(unsigned short*)((char*)s_t + ((row * 256 + col * 2) ^ ((row & 7) << 4)))
                = f2b(softplus_f(acc[r] + bias));
        }
    }
    __syncthreads();
    bf16x8 a2[4];
#pragma unroll
    for (int ks = 0; ks < 4; ++ks)
        a2[ks] = *(const bf16x8*)((char*)s_t +
                 ((lr * 256 + (ks * 32 + lg * 8) * 2) ^ ((lr & 7) << 4)));
    {
        f32x4 acc = {0.f, 0.f, 0.f, 0.f};
#pragma unroll
        for (int ks = 0; ks < 4; ++ks)
            acc = __builtin_amdgcn_mfma_f32_16x16x32_bf16(
                a2[ks], *(const bf16x8*)&wdenseB[((ks * 8 + ct) * 64 + lane) * 8],
                acc, 0, 0, 0);
        const int col = ct * 16 + lr;
        const float bias = b_dense[col];
#pragma unroll
        for (int r = 0; r < 4; ++r)
            out[(size_t)(n0 + lg * 4 + r) * 256 + FD + col] = acc[r] + bias;
    }
}

extern "C" void kernel_launch(void* const* d_in, const int* in_sizes, int n_in,
                              void* d_out, int out_size, void* d_ws, size_t ws_size,
                              hipStream_t stream)
{
    const float* positions = (const float*)d_in[0];
    const float* cell      = (const float*)d_in[1];
    const float* coff      = (const float*)d_in[2];
    const float* nmask     = (const float*)d_in[3];
    const float* emb       = (const float*)d_in[4];
    const float* wf1       = (const float*)d_in[5];
    const float* bf1       = (const float*)d_in[6];
    const float* wf2       = (const float*)d_in[7];
    const float* bf2       = (const float*)d_in[8];
    const float* w_in2f    = (const float*)d_in[9];
    const float* w_f2out   = (const float*)d_in[10];
    const float* b_f2out   = (const float*)d_in[11];
    const float* w_dense   = (const float*)d_in[12];
    const float* b_dense   = (const float*)d_in[13];
    const int*   zn        = (const int*)d_in[14];
    const int*   nbr       = (const int*)d_in[15];
    const int*   label     = (const int*)d_in[16];

    float* out = (float*)d_out;
    float* ws  = (float*)d_ws;
    float* y   = ws;                       // [4096,128]
    float* agg = ws + BN * FD;             // [4096,128]
    unsigned short* wf1tA   = (unsigned short*)(ws + 2 * BN * FD);  // 4096
    unsigned short* wf2tA   = wf1tA + 4096;                         // 16384
    unsigned short* wf2outB = wf2tA + 16384;                        // 16384
    unsigned short* wdenseB = wf2outB + 16384;                      // 16384

    hipLaunchKernelGGL(kA_prep_embed_y, dim3(BN / 16), dim3(512), 0, stream,
                       emb, zn, wf1, wf2, w_in2f, w_f2out, w_dense,
                       wf1tA, wf2tA, wf2outB, wdenseB, y, out);
    hipLaunchKernelGGL(kB_conv, dim3(BN), dim3(256), 0, stream,
                       positions, cell, coff, nmask, wf1tA, bf1, wf2tA, bf2,
                       nbr, y, agg);
    hipLaunchKernelGGL(kC_post_gather, dim3(BN / 16), dim3(512), 0, stream,
                       agg, label, wf2outB, b_f2out, wdenseB, b_dense, out);
}